// Round 3
// baseline (1722.444 us; speedup 1.0000x reference)
//
#include <hip/hip_runtime.h>
#include <hip/hip_fp16.h>

// GCN: h1 = relu(gcn(x,W1,b1)); h2 = relu(gcn(h1,W2,b2)); out = h2.reshape(B,896)@Wfc + bfc
// Factored: g1 = dinv*(x@W1); h1 = relu(dinv*agg(g1)+b1); u1 = dinv*h1;
//           a2 = dinv*agg(u1);  h2 = relu(a2@W2+b2)  [since agg commutes with @W2]
//           out[g] = sum_t sum_j h2[g*14+t,j]*Wfc[t*64+j] + bfc
// Features stored fp16 (two N*64 buffers). Workspace ~197MiB; gated on ws_size.

__global__ __launch_bounds__(256) void fallback_kernel(float* __restrict__ out, int n, float v)
{
  int i = blockIdx.x * 256 + threadIdx.x;
  if (i < n) out[i] = v;
}

// detect edges dtype: int64 values < 2^31 -> every odd int32 word is 0
__global__ __launch_bounds__(64) void probe_kernel(const int* __restrict__ edges, int* __restrict__ flag)
{
  if (threadIdx.x == 0) {
    int orv = edges[1] | edges[3] | edges[5] | edges[7] | edges[9] | edges[11] | edges[13] | edges[15];
    flag[0] = (orv == 0) ? 1 : 0;  // 1 => int64 layout (shift word index by 1)
  }
}

__global__ __launch_bounds__(256) void zero_i32_kernel(int* __restrict__ p, int n)
{
  int i = blockIdx.x * 256 + threadIdx.x;
  if (i < n) p[i] = 0;
}

__global__ __launch_bounds__(256) void count_kernel(
    const int* __restrict__ edges, int E, int N, const int* __restrict__ flag,
    int* __restrict__ count)
{
  int e = blockIdx.x * 256 + threadIdx.x;
  if (e >= E) return;
  int sh = flag[0];
  int d = edges[(E + e) << sh];
  if ((unsigned)d < (unsigned)N) atomicAdd(&count[d], 1);
}

__global__ __launch_bounds__(1024) void scan_block_kernel(
    const int* __restrict__ count, int n, int* __restrict__ excl, int* __restrict__ bsum)
{
  __shared__ int sm[1024];
  int t = threadIdx.x;
  int i = blockIdx.x * 1024 + t;
  int v = (i < n) ? count[i] : 0;
  sm[t] = v;
  __syncthreads();
  for (int off = 1; off < 1024; off <<= 1) {
    int x = 0;
    if (t >= off) x = sm[t - off];
    __syncthreads();
    if (t >= off) sm[t] += x;
    __syncthreads();
  }
  if (i < n) excl[i] = sm[t] - v;
  if (t == 1023) bsum[blockIdx.x] = sm[1023];
}

__global__ __launch_bounds__(1024) void scan_bsum_kernel(int* __restrict__ bsum, int nb)
{
  __shared__ int sm[1024];
  int t = threadIdx.x;
  int v = (t < nb) ? bsum[t] : 0;
  sm[t] = v;
  __syncthreads();
  for (int off = 1; off < 1024; off <<= 1) {
    int x = 0;
    if (t >= off) x = sm[t - off];
    __syncthreads();
    if (t >= off) sm[t] += x;
    __syncthreads();
  }
  if (t < nb) bsum[t] = sm[t] - v;  // exclusive block offsets
}

__global__ __launch_bounds__(256) void finalize_kernel(
    int* __restrict__ rowptr, const int* __restrict__ bsum,
    const int* __restrict__ count, int* __restrict__ cursor,
    float* __restrict__ dinv, int n, int E)
{
  int i = blockIdx.x * 256 + threadIdx.x;
  if (i >= n) return;
  int r = rowptr[i] + bsum[i >> 10];
  rowptr[i] = r;
  cursor[i] = r;
  dinv[i] = rsqrtf((float)(count[i] + 1));  // deg = dst-count + 1 (self loop)
  if (i == 0) rowptr[n] = E;
}

__global__ __launch_bounds__(256) void fill_kernel(
    const int* __restrict__ edges, int E, int N, const int* __restrict__ flag,
    int* __restrict__ cursor, int* __restrict__ col)
{
  int e = blockIdx.x * 256 + threadIdx.x;
  if (e >= E) return;
  int sh = flag[0];
  int s = edges[e << sh];
  int d = edges[(E + e) << sh];
  if ((unsigned)d >= (unsigned)N || (unsigned)s >= (unsigned)N) return;
  int pos = atomicAdd(&cursor[d], 1);
  if ((unsigned)pos < (unsigned)E) col[pos] = s;
}

// g1[n,j] = dinv[n] * sum_k x[n,k]*W1[k,j]   (K=32, wave per node, lane=j, grid-stride)
__global__ __launch_bounds__(256) void mm1_kernel(
    const float* __restrict__ X, const float* __restrict__ W1,
    const float* __restrict__ dinv, __half* __restrict__ G, int n)
{
  int lane = threadIdx.x & 63;
  float Wr[32];
#pragma unroll
  for (int k = 0; k < 32; k++) Wr[k] = W1[k * 64 + lane];
  int wave = (blockIdx.x * 256 + threadIdx.x) >> 6;
  int nw = (gridDim.x * 256) >> 6;
  for (int node = wave; node < n; node += nw) {
    int un = __builtin_amdgcn_readfirstlane(node);
    float xv = X[(size_t)un * 32 + (lane & 31)];  // lanes 0..31 hold the row
    float acc = 0.f;
#pragma unroll
    for (int k = 0; k < 32; k++) acc += __shfl(xv, k) * Wr[k];
    G[(size_t)un * 64 + lane] = __float2half(dinv[un] * acc);
  }
}

// u1[n,:] = dinv[n] * relu(dinv[n]*(sum_{e in row n} g1[col[e],:] + g1[n,:]) + b1)
__global__ __launch_bounds__(256) void agg1_kernel(
    const __half* __restrict__ G, const int* __restrict__ rowptr,
    const int* __restrict__ col, const float* __restrict__ dinv,
    const float* __restrict__ bias, __half* __restrict__ U, int n)
{
  int lane = threadIdx.x & 63;
  int wave = (blockIdx.x * 256 + threadIdx.x) >> 6;
  if (wave >= n) return;
  int un = __builtin_amdgcn_readfirstlane(wave);
  float di = dinv[un];
  float acc = __half2float(G[(size_t)un * 64 + lane]);
  int e = rowptr[un], end = rowptr[un + 1];
  for (; e + 4 <= end; e += 4) {
    int s0 = col[e], s1 = col[e + 1], s2 = col[e + 2], s3 = col[e + 3];
    float v0 = __half2float(G[(size_t)s0 * 64 + lane]);
    float v1 = __half2float(G[(size_t)s1 * 64 + lane]);
    float v2 = __half2float(G[(size_t)s2 * 64 + lane]);
    float v3 = __half2float(G[(size_t)s3 * 64 + lane]);
    acc += (v0 + v1) + (v2 + v3);
  }
  for (; e < end; e++) acc += __half2float(G[(size_t)col[e] * 64 + lane]);
  float h = di * acc + bias[lane];
  h = h > 0.f ? h : 0.f;
  U[(size_t)un * 64 + lane] = __float2half(di * h);
}

// a2[n,:] = dinv[n] * (sum_{e in row n} u1[col[e],:] + u1[n,:])
__global__ __launch_bounds__(256) void agg2_kernel(
    const __half* __restrict__ U, const int* __restrict__ rowptr,
    const int* __restrict__ col, const float* __restrict__ dinv,
    __half* __restrict__ A2, int n)
{
  int lane = threadIdx.x & 63;
  int wave = (blockIdx.x * 256 + threadIdx.x) >> 6;
  if (wave >= n) return;
  int un = __builtin_amdgcn_readfirstlane(wave);
  float acc = __half2float(U[(size_t)un * 64 + lane]);
  int e = rowptr[un], end = rowptr[un + 1];
  for (; e + 4 <= end; e += 4) {
    int s0 = col[e], s1 = col[e + 1], s2 = col[e + 2], s3 = col[e + 3];
    float v0 = __half2float(U[(size_t)s0 * 64 + lane]);
    float v1 = __half2float(U[(size_t)s1 * 64 + lane]);
    float v2 = __half2float(U[(size_t)s2 * 64 + lane]);
    float v3 = __half2float(U[(size_t)s3 * 64 + lane]);
    acc += (v0 + v1) + (v2 + v3);
  }
  for (; e < end; e++) acc += __half2float(U[(size_t)col[e] * 64 + lane]);
  A2[(size_t)un * 64 + lane] = __float2half(dinv[un] * acc);
}

__global__ __launch_bounds__(256) void out_init_kernel(
    float* __restrict__ out, const float* __restrict__ bfc, int n)
{
  int i = blockIdx.x * 256 + threadIdx.x;
  if (i < n) out[i] = bfc[0];
}

// h2[n,j] = relu(sum_k a2[n,k]*W2[k,j] + b2[j]); out[n/14] += sum_j h2[n,j]*Wfc[(n%14)*64+j]
__global__ __launch_bounds__(256) void final_kernel(
    const __half* __restrict__ A2, const float* __restrict__ W2,
    const float* __restrict__ b2, const float* __restrict__ Wfc,
    float* __restrict__ out, int n)
{
  int lane = threadIdx.x & 63;
  float W2r[64];
#pragma unroll
  for (int k = 0; k < 64; k++) W2r[k] = W2[k * 64 + lane];
  float bb = b2[lane];
  int wave = (blockIdx.x * 256 + threadIdx.x) >> 6;
  int nw = (gridDim.x * 256) >> 6;
  for (int node = wave; node < n; node += nw) {
    int un = __builtin_amdgcn_readfirstlane(node);
    float av = __half2float(A2[(size_t)un * 64 + lane]);
    float acc = bb;
#pragma unroll
    for (int k = 0; k < 64; k++) acc += __shfl(av, k) * W2r[k];
    acc = acc > 0.f ? acc : 0.f;
    int g = un / 14;
    int t = un - g * 14;
    float p = acc * Wfc[t * 64 + lane];
#pragma unroll
    for (int off = 32; off; off >>= 1) p += __shfl_down(p, off);
    if (lane == 0) atomicAdd(&out[g], p);
  }
}

extern "C" void kernel_launch(void* const* d_in, const int* in_sizes, int n_in,
                              void* d_out, int out_size, void* d_ws, size_t ws_size,
                              hipStream_t stream)
{
  const float* x = (const float*)d_in[0];
  const int* edges = (const int*)d_in[1];
  const float* W1 = (const float*)d_in[2];
  const float* b1 = (const float*)d_in[3];
  const float* W2 = (const float*)d_in[4];
  const float* b2 = (const float*)d_in[5];
  const float* Wfc = (const float*)d_in[6];
  const float* bfc = (const float*)d_in[7];
  float* out = (float*)d_out;
  (void)n_in;

  const int N = in_sizes[0] / 32;  // 700000
  const int E = in_sizes[1] / 2;   // 4000000
  const int B = out_size;          // 50000

  // workspace layout (256B-aligned chunks)
  char* ws = (char*)d_ws;
  size_t off = 0;
  auto alloc = [&](size_t bytes) -> void* {
    void* p = ws + off;
    off += (bytes + 255) & ~(size_t)255;
    return p;
  };
  int* flag = (int*)alloc(256);
  int* col = (int*)alloc((size_t)E * 4);
  int* count = (int*)alloc((size_t)N * 4);
  int* rowptr = (int*)alloc(((size_t)N + 1) * 4);
  int* cursor = (int*)alloc((size_t)N * 4);
  float* dinv = (float*)alloc((size_t)N * 4);
  int* bsum = (int*)alloc(4096);
  __half* F1 = (__half*)alloc((size_t)N * 64 * 2);  // g1, later a2
  __half* F2 = (__half*)alloc((size_t)N * 64 * 2);  // u1

  if (off > ws_size) {
    // workspace too small: report its size via d_out (absmax ~= ws_size in MB)
    float v = -(float)(double)(ws_size >> 20);
    fallback_kernel<<<(B + 255) / 256, 256, 0, stream>>>(out, B, v);
    return;
  }

  probe_kernel<<<1, 64, 0, stream>>>(edges, flag);
  zero_i32_kernel<<<(N + 255) / 256, 256, 0, stream>>>(count, N);
  count_kernel<<<(E + 255) / 256, 256, 0, stream>>>(edges, E, N, flag, count);
  int NB = (N + 1023) / 1024;  // 684 <= 1024
  scan_block_kernel<<<NB, 1024, 0, stream>>>(count, N, rowptr, bsum);
  scan_bsum_kernel<<<1, 1024, 0, stream>>>(bsum, NB);
  finalize_kernel<<<(N + 255) / 256, 256, 0, stream>>>(rowptr, bsum, count, cursor, dinv, N, E);
  fill_kernel<<<(E + 255) / 256, 256, 0, stream>>>(edges, E, N, flag, cursor, col);

  int aggBlocks = (N * 64 + 255) / 256;  // one wave per node
  mm1_kernel<<<8192, 256, 0, stream>>>(x, W1, dinv, F1, N);
  agg1_kernel<<<aggBlocks, 256, 0, stream>>>(F1, rowptr, col, dinv, b1, F2, N);
  agg2_kernel<<<aggBlocks, 256, 0, stream>>>(F2, rowptr, col, dinv, F1, N);
  out_init_kernel<<<(B + 255) / 256, 256, 0, stream>>>(out, bfc, B);
  final_kernel<<<8192, 256, 0, stream>>>(F1, W2, b2, Wfc, out, N);
}

// Round 4
// 1390.784 us; speedup vs baseline: 1.2385x; 1.2385x over previous
//
#include <hip/hip_runtime.h>
#include <hip/hip_fp16.h>

// GCN: h1 = relu(gcn(x,W1,b1)); h2 = relu(gcn(h1,W2,b2)); out = h2.reshape(B,896)@Wfc + bfc
// Factored: g1 = dinv*(x@W1); h1 = relu(dinv*agg(g1)+b1); u1 = dinv*h1;
//           a2 = dinv*agg(u1);  h2 = relu(a2@W2+b2)  [agg commutes with @W2]
//           out[g] = sum_t sum_j h2[g*14+t,j]*Wfc[t*64+j] + bfc
// Layer2 matmul+FC fused on MFMA (fp16 16x16x32). Features fp16, two N*64 buffers.

typedef _Float16 half8 __attribute__((ext_vector_type(8)));
typedef float float4v __attribute__((ext_vector_type(4)));

__global__ __launch_bounds__(256) void fallback_kernel(float* __restrict__ out, int n, float v)
{
  int i = blockIdx.x * 256 + threadIdx.x;
  if (i < n) out[i] = v;
}

// detect edges dtype: int64 values < 2^31 -> every odd int32 word is 0
__global__ __launch_bounds__(64) void probe_kernel(const int* __restrict__ edges, int* __restrict__ flag)
{
  if (threadIdx.x == 0) {
    int orv = edges[1] | edges[3] | edges[5] | edges[7] | edges[9] | edges[11] | edges[13] | edges[15];
    flag[0] = (orv == 0) ? 1 : 0;  // 1 => int64 layout (shift word index by 1)
  }
}

__global__ __launch_bounds__(256) void zero_i32_kernel(int* __restrict__ p, int n)
{
  int i = blockIdx.x * 256 + threadIdx.x;
  if (i < n) p[i] = 0;
}

__global__ __launch_bounds__(256) void count_kernel(
    const int* __restrict__ edges, int E, int N, const int* __restrict__ flag,
    int* __restrict__ count)
{
  int e = blockIdx.x * 256 + threadIdx.x;
  if (e >= E) return;
  int sh = flag[0];
  int d = edges[(E + e) << sh];
  if ((unsigned)d < (unsigned)N) atomicAdd(&count[d], 1);
}

__global__ __launch_bounds__(1024) void scan_block_kernel(
    const int* __restrict__ count, int n, int* __restrict__ excl, int* __restrict__ bsum)
{
  __shared__ int sm[1024];
  int t = threadIdx.x;
  int i = blockIdx.x * 1024 + t;
  int v = (i < n) ? count[i] : 0;
  sm[t] = v;
  __syncthreads();
  for (int off = 1; off < 1024; off <<= 1) {
    int x = 0;
    if (t >= off) x = sm[t - off];
    __syncthreads();
    if (t >= off) sm[t] += x;
    __syncthreads();
  }
  if (i < n) excl[i] = sm[t] - v;
  if (t == 1023) bsum[blockIdx.x] = sm[1023];
}

__global__ __launch_bounds__(1024) void scan_bsum_kernel(int* __restrict__ bsum, int nb)
{
  __shared__ int sm[1024];
  int t = threadIdx.x;
  int v = (t < nb) ? bsum[t] : 0;
  sm[t] = v;
  __syncthreads();
  for (int off = 1; off < 1024; off <<= 1) {
    int x = 0;
    if (t >= off) x = sm[t - off];
    __syncthreads();
    if (t >= off) sm[t] += x;
    __syncthreads();
  }
  if (t < nb) bsum[t] = sm[t] - v;  // exclusive block offsets
}

__global__ __launch_bounds__(256) void finalize_kernel(
    int* __restrict__ rowptr, const int* __restrict__ bsum,
    const int* __restrict__ count, int* __restrict__ cursor,
    float* __restrict__ dinv, int n, int E)
{
  int i = blockIdx.x * 256 + threadIdx.x;
  if (i >= n) return;
  int r = rowptr[i] + bsum[i >> 10];
  rowptr[i] = r;
  cursor[i] = r;
  dinv[i] = rsqrtf((float)(count[i] + 1));  // deg = dst-count + 1 (self loop)
  if (i == 0) rowptr[n] = E;
}

__global__ __launch_bounds__(256) void fill_kernel(
    const int* __restrict__ edges, int E, int N, const int* __restrict__ flag,
    int* __restrict__ cursor, int* __restrict__ col)
{
  int e = blockIdx.x * 256 + threadIdx.x;
  if (e >= E) return;
  int sh = flag[0];
  int s = edges[e << sh];
  int d = edges[(E + e) << sh];
  if ((unsigned)d >= (unsigned)N || (unsigned)s >= (unsigned)N) return;
  int pos = atomicAdd(&cursor[d], 1);
  if ((unsigned)pos < (unsigned)E) col[pos] = s;
}

// g1[n,j] = dinv[n] * sum_k x[n,k]*W1[k,j]   (K=32, wave per node, lane=j, grid-stride)
__global__ __launch_bounds__(256) void mm1_kernel(
    const float* __restrict__ X, const float* __restrict__ W1,
    const float* __restrict__ dinv, __half* __restrict__ G, int n)
{
  int lane = threadIdx.x & 63;
  float Wr[32];
#pragma unroll
  for (int k = 0; k < 32; k++) Wr[k] = W1[k * 64 + lane];
  int wave = (blockIdx.x * 256 + threadIdx.x) >> 6;
  int nw = (gridDim.x * 256) >> 6;
  for (int node = wave; node < n; node += nw) {
    int un = __builtin_amdgcn_readfirstlane(node);
    float xv = X[(size_t)un * 32 + (lane & 31)];  // lanes 0..31 hold the row
    float acc = 0.f;
#pragma unroll
    for (int k = 0; k < 32; k++) acc += __shfl(xv, k) * Wr[k];
    G[(size_t)un * 64 + lane] = __float2half(dinv[un] * acc);
  }
}

// u1[n,:] = dinv[n] * relu(dinv[n]*(sum_{e in row n} g1[col[e],:] + g1[n,:]) + b1)
__global__ __launch_bounds__(256) void agg1_kernel(
    const __half* __restrict__ G, const int* __restrict__ rowptr,
    const int* __restrict__ col, const float* __restrict__ dinv,
    const float* __restrict__ bias, __half* __restrict__ U, int n)
{
  int lane = threadIdx.x & 63;
  int wave = (blockIdx.x * 256 + threadIdx.x) >> 6;
  if (wave >= n) return;
  int un = __builtin_amdgcn_readfirstlane(wave);
  float di = dinv[un];
  float acc = __half2float(G[(size_t)un * 64 + lane]);
  int e = rowptr[un], end = rowptr[un + 1];
  for (; e + 8 <= end; e += 8) {
    float v0 = __half2float(G[(size_t)col[e + 0] * 64 + lane]);
    float v1 = __half2float(G[(size_t)col[e + 1] * 64 + lane]);
    float v2 = __half2float(G[(size_t)col[e + 2] * 64 + lane]);
    float v3 = __half2float(G[(size_t)col[e + 3] * 64 + lane]);
    float v4 = __half2float(G[(size_t)col[e + 4] * 64 + lane]);
    float v5 = __half2float(G[(size_t)col[e + 5] * 64 + lane]);
    float v6 = __half2float(G[(size_t)col[e + 6] * 64 + lane]);
    float v7 = __half2float(G[(size_t)col[e + 7] * 64 + lane]);
    acc += ((v0 + v1) + (v2 + v3)) + ((v4 + v5) + (v6 + v7));
  }
  for (; e < end; e++) acc += __half2float(G[(size_t)col[e] * 64 + lane]);
  float h = di * acc + bias[lane];
  h = h > 0.f ? h : 0.f;
  U[(size_t)un * 64 + lane] = __float2half(di * h);
}

// a2[n,:] = dinv[n] * (sum_{e in row n} u1[col[e],:] + u1[n,:])
__global__ __launch_bounds__(256) void agg2_kernel(
    const __half* __restrict__ U, const int* __restrict__ rowptr,
    const int* __restrict__ col, const float* __restrict__ dinv,
    __half* __restrict__ A2, int n)
{
  int lane = threadIdx.x & 63;
  int wave = (blockIdx.x * 256 + threadIdx.x) >> 6;
  if (wave >= n) return;
  int un = __builtin_amdgcn_readfirstlane(wave);
  float acc = __half2float(U[(size_t)un * 64 + lane]);
  int e = rowptr[un], end = rowptr[un + 1];
  for (; e + 8 <= end; e += 8) {
    float v0 = __half2float(U[(size_t)col[e + 0] * 64 + lane]);
    float v1 = __half2float(U[(size_t)col[e + 1] * 64 + lane]);
    float v2 = __half2float(U[(size_t)col[e + 2] * 64 + lane]);
    float v3 = __half2float(U[(size_t)col[e + 3] * 64 + lane]);
    float v4 = __half2float(U[(size_t)col[e + 4] * 64 + lane]);
    float v5 = __half2float(U[(size_t)col[e + 5] * 64 + lane]);
    float v6 = __half2float(U[(size_t)col[e + 6] * 64 + lane]);
    float v7 = __half2float(U[(size_t)col[e + 7] * 64 + lane]);
    acc += ((v0 + v1) + (v2 + v3)) + ((v4 + v5) + (v6 + v7));
  }
  for (; e < end; e++) acc += __half2float(U[(size_t)col[e] * 64 + lane]);
  A2[(size_t)un * 64 + lane] = __float2half(dinv[un] * acc);
}

__global__ __launch_bounds__(256) void out_init_kernel(
    float* __restrict__ out, const float* __restrict__ bfc, int n)
{
  int i = blockIdx.x * 256 + threadIdx.x;
  if (i < n) out[i] = bfc[0];
}

// MFMA fused layer2-matmul + relu + FC:
// per wave: 16 nodes; D[16 nodes][64 j] = A2tile @ W2 via 8x mfma_f32_16x16x32_f16;
// h2 = relu(D + b2); out[node/14] += sum_j h2[node][j]*Wfc[(node%14)*64+j]
// A-frag: lane holds A[m=lane&15][k=quad*8+i]; B-frag: B[k=quad*8+i][n=lane&15]
// C/D:    lane holds D[row=quad*4+r][col=lane&15]
__global__ __launch_bounds__(256) void mfma_final_kernel(
    const __half* __restrict__ A2, const float* __restrict__ W2,
    const float* __restrict__ b2, const float* __restrict__ Wfc,
    float* __restrict__ out, int ntiles)
{
  int lane = threadIdx.x & 63;
  int n16 = lane & 15;
  int quad = lane >> 4;

  // B fragments for W2 (f32 -> f16), 4 j-tiles x 2 k-frags
  half8 bf[4][2];
#pragma unroll
  for (int jb = 0; jb < 4; jb++)
#pragma unroll
    for (int kf = 0; kf < 2; kf++)
#pragma unroll
      for (int i = 0; i < 8; i++)
        bf[jb][kf][i] = (_Float16)W2[(kf * 32 + quad * 8 + i) * 64 + jb * 16 + n16];
  float b2j[4];
#pragma unroll
  for (int jb = 0; jb < 4; jb++) b2j[jb] = b2[jb * 16 + n16];

  const _Float16* A2h = (const _Float16*)A2;
  int wave = (blockIdx.x * 256 + threadIdx.x) >> 6;
  int nw = (gridDim.x * 256) >> 6;
  for (int tile = wave; tile < ntiles; tile += nw) {
    int ut = __builtin_amdgcn_readfirstlane(tile);
    int base = ut * 16;
    // A fragments: node = base + n16, k = kf*32 + quad*8 + i  (16B vector loads)
    const _Float16* arow = A2h + (size_t)(base + n16) * 64 + quad * 8;
    half8 a0 = *(const half8*)(arow);
    half8 a1 = *(const half8*)(arow + 32);

    // per-r node constants (same across jb)
    int g_r[4], t_r[4];
#pragma unroll
    for (int r = 0; r < 4; r++) {
      int node = base + quad * 4 + r;
      g_r[r] = node / 14;
      t_r[r] = node - g_r[r] * 14;
    }
    float pr[4] = {0.f, 0.f, 0.f, 0.f};
#pragma unroll
    for (int jb = 0; jb < 4; jb++) {
      float4v acc = {0.f, 0.f, 0.f, 0.f};
      acc = __builtin_amdgcn_mfma_f32_16x16x32_f16(a0, bf[jb][0], acc, 0, 0, 0);
      acc = __builtin_amdgcn_mfma_f32_16x16x32_f16(a1, bf[jb][1], acc, 0, 0, 0);
      int j = jb * 16 + n16;
#pragma unroll
      for (int r = 0; r < 4; r++) {
        float h = acc[r] + b2j[jb];
        h = h > 0.f ? h : 0.f;
        pr[r] += h * Wfc[t_r[r] * 64 + j];
      }
    }
    // reduce pr across the 16 lanes of this quad-group
#pragma unroll
    for (int r = 0; r < 4; r++) {
#pragma unroll
      for (int off = 1; off < 16; off <<= 1) pr[r] += __shfl_xor(pr[r], off);
    }
    if (n16 == 0) {
#pragma unroll
      for (int r = 0; r < 4; r++) atomicAdd(&out[g_r[r]], pr[r]);
    }
  }
}

extern "C" void kernel_launch(void* const* d_in, const int* in_sizes, int n_in,
                              void* d_out, int out_size, void* d_ws, size_t ws_size,
                              hipStream_t stream)
{
  const float* x = (const float*)d_in[0];
  const int* edges = (const int*)d_in[1];
  const float* W1 = (const float*)d_in[2];
  const float* b1 = (const float*)d_in[3];
  const float* W2 = (const float*)d_in[4];
  const float* b2 = (const float*)d_in[5];
  const float* Wfc = (const float*)d_in[6];
  const float* bfc = (const float*)d_in[7];
  float* out = (float*)d_out;
  (void)n_in;

  const int N = in_sizes[0] / 32;  // 700000
  const int E = in_sizes[1] / 2;   // 4000000
  const int B = out_size;          // 50000

  char* ws = (char*)d_ws;
  size_t off = 0;
  auto alloc = [&](size_t bytes) -> void* {
    void* p = ws + off;
    off += (bytes + 255) & ~(size_t)255;
    return p;
  };
  int* flag = (int*)alloc(256);
  int* col = (int*)alloc((size_t)E * 4);
  int* count = (int*)alloc((size_t)N * 4);
  int* rowptr = (int*)alloc(((size_t)N + 1) * 4);
  int* cursor = (int*)alloc((size_t)N * 4);
  float* dinv = (float*)alloc((size_t)N * 4);
  int* bsum = (int*)alloc(4096);
  __half* F1 = (__half*)alloc(((size_t)N + 16) * 64 * 2);  // g1, later a2
  __half* F2 = (__half*)alloc(((size_t)N + 16) * 64 * 2);  // u1

  if (off > ws_size) {
    float v = -(float)(double)(ws_size >> 20);
    fallback_kernel<<<(B + 255) / 256, 256, 0, stream>>>(out, B, v);
    return;
  }

  probe_kernel<<<1, 64, 0, stream>>>(edges, flag);
  zero_i32_kernel<<<(N + 255) / 256, 256, 0, stream>>>(count, N);
  count_kernel<<<(E + 255) / 256, 256, 0, stream>>>(edges, E, N, flag, count);
  int NB = (N + 1023) / 1024;  // 684 <= 1024
  scan_block_kernel<<<NB, 1024, 0, stream>>>(count, N, rowptr, bsum);
  scan_bsum_kernel<<<1, 1024, 0, stream>>>(bsum, NB);
  finalize_kernel<<<(N + 255) / 256, 256, 0, stream>>>(rowptr, bsum, count, cursor, dinv, N, E);
  fill_kernel<<<(E + 255) / 256, 256, 0, stream>>>(edges, E, N, flag, cursor, col);

  int aggBlocks = (N * 64 + 255) / 256;  // one wave per node
  mm1_kernel<<<8192, 256, 0, stream>>>(x, W1, dinv, F1, N);
  agg1_kernel<<<aggBlocks, 256, 0, stream>>>(F1, rowptr, col, dinv, b1, F2, N);
  agg2_kernel<<<aggBlocks, 256, 0, stream>>>(F2, rowptr, col, dinv, F1, N);
  out_init_kernel<<<(B + 255) / 256, 256, 0, stream>>>(out, bfc, B);
  int ntiles = (N + 15) / 16;  // 43750
  mfma_final_kernel<<<2048, 256, 0, stream>>>(F1, W2, b2, Wfc, out, ntiles);
}